// Round 5
// baseline (174.151 us; speedup 1.0000x reference)
//
#include <hip/hip_runtime.h>

// GRU trajectory decoder, fused single kernel. B=16384, D=256, HID=128, T=60, O=3.
// R5: 256-thr blocks (4 waves, 32 batch rows), grid=512 -> 2 independent
// blocks/CU so barrier stalls of one block overlap with the other's issue.
// Wave w owns hid dims [32w,32w+32) (2 m-subtiles x 3 gates x 4 K-tiles of
// mfma_f32_16x16x32_bf16); W_hh frags (96 regs) + gi (MFMA C-init) persistent.
// h through double-buffered LDS tile, 16B-chunk XOR swizzle (conflict-free).
// Gate math: shared-rcp sigmoid pair (5 trans/elem, was 6); h-writeback via
// v_cvt_pk_bf16_f32. 2 waves/SIMD (256-reg budget) -- 4 waves/SIMD spills (R2).

typedef __attribute__((ext_vector_type(8))) short short8;
typedef __attribute__((ext_vector_type(4))) float f32x4;

#define MFMA16(a, b, c) __builtin_amdgcn_mfma_f32_16x16x32_bf16((a), (b), (c), 0, 0, 0)

__device__ __forceinline__ short f2bf(float x) {
    union { float f; unsigned u; } v; v.f = x;
    unsigned r = v.u + 0x7FFFu + ((v.u >> 16) & 1u);   // RNE
    return (short)(r >> 16);
}

__device__ __forceinline__ unsigned cvtpk(float lo, float hi) {
    unsigned d;
    asm("v_cvt_pk_bf16_f32 %0, %1, %2" : "=v"(d) : "v"(lo), "v"(hi));
    return d;
}

__device__ __forceinline__ short8 cvt8(const float* __restrict__ p) {
    f32x4 a = *(const f32x4*)p;
    f32x4 b = *(const f32x4*)(p + 4);
    short8 r;
    r[0] = f2bf(a[0]); r[1] = f2bf(a[1]); r[2] = f2bf(a[2]); r[3] = f2bf(a[3]);
    r[4] = f2bf(b[0]); r[5] = f2bf(b[1]); r[6] = f2bf(b[2]); r[7] = f2bf(b[3]);
    return r;
}

__global__ __launch_bounds__(256, 2) void gru_traj_kernel(
    const float* __restrict__ x,      // [B,256]
    const float* __restrict__ W_ih,   // [384,256]
    const float* __restrict__ W_hh,   // [384,128]
    const float* __restrict__ b_ih,   // [384]
    const float* __restrict__ b_hh,   // [384]
    const float* __restrict__ W_out,  // [3,128]
    const float* __restrict__ b_out,  // [3]
    float* __restrict__ out)          // [B,60,3]
{
    const int tid  = threadIdx.x;
    const int wid  = tid >> 6;          // wave 0..3 -> 32 hid dims
    const int lane = tid & 63;
    const int l15  = lane & 15;
    const int l4   = lane >> 4;         // 0..3
    const int b0   = blockIdx.x << 5;   // 32 batch rows per block
    const int hb   = wid << 5;          // wave's hid base

    // h^T staging: [32 batch rows][128 hid] bf16, 16B-chunk XOR swizzle, dbuf
    __shared__ short hbuf[2][32 * 128];
    __shared__ short wobuf[3 * 136];    // W_out bf16, padded rows

    {   // h_0 = 0
        int* z = (int*)hbuf[0];
        #pragma unroll
        for (int i = 0; i < 8; ++i) z[tid + i * 256] = 0;
    }
    for (int i = tid; i < 384; i += 256)
        wobuf[(i >> 7) * 136 + (i & 127)] = f2bf(W_out[i]);

    // ---- persistent W_hh A-frags: A[m'=l15][k] = W_hh[g*128+hb+m*16+l15][k]
    short8 wfrag[2][3][4];
    #pragma unroll
    for (int m = 0; m < 2; ++m)
        #pragma unroll
        for (int g = 0; g < 3; ++g)
            #pragma unroll
            for (int kt = 0; kt < 4; ++kt)
                wfrag[m][g][kt] = cvt8(W_hh + (size_t)(g * 128 + hb + m * 16 + l15) * 128 + kt * 32 + l4 * 8);

    // biases over this lane's 4 hid dims per m-subtile (D rows l4*4+r)
    f32x4 bNh[2];
    f32x4 bR[2], bZ[2], bNi[2];
    #pragma unroll
    for (int m = 0; m < 2; ++m) {
        const int base = hb + m * 16 + l4 * 4;
        bR[m]  = *(const f32x4*)(b_ih + base)       + *(const f32x4*)(b_hh + base);
        bZ[m]  = *(const f32x4*)(b_ih + 128 + base) + *(const f32x4*)(b_hh + 128 + base);
        bNi[m] = *(const f32x4*)(b_ih + 256 + base);
        bNh[m] = *(const f32x4*)(b_hh + 256 + base);
    }
    const float bo0 = b_out[0], bo1 = b_out[1], bo2 = b_out[2];

    // ---- prologue: gi^T = W_ih * x^T per (q batch-chunk, m subtile) ----
    f32x4 initR[2][2], initZ[2][2], giN[2][2];
    #pragma unroll
    for (int q = 0; q < 2; ++q)
        #pragma unroll
        for (int m = 0; m < 2; ++m) { initR[q][m] = bR[m]; initZ[q][m] = bZ[m]; giN[q][m] = bNi[m]; }
    #pragma unroll
    for (int kt = 0; kt < 8; ++kt) {
        short8 a_[2][3];
        #pragma unroll
        for (int m = 0; m < 2; ++m)
            #pragma unroll
            for (int g = 0; g < 3; ++g)
                a_[m][g] = cvt8(W_ih + (size_t)(g * 128 + hb + m * 16 + l15) * 256 + kt * 32 + l4 * 8);
        #pragma unroll
        for (int q = 0; q < 2; ++q) {
            short8 bx = cvt8(x + (size_t)(b0 + q * 16 + l15) * 256 + kt * 32 + l4 * 8);
            #pragma unroll
            for (int m = 0; m < 2; ++m) {
                initR[q][m] = MFMA16(a_[m][0], bx, initR[q][m]);
                initZ[q][m] = MFMA16(a_[m][1], bx, initZ[q][m]);
                giN [q][m] = MFMA16(a_[m][2], bx, giN [q][m]);
            }
        }
    }

    float hq[2][2][4];
    #pragma unroll
    for (int q = 0; q < 2; ++q)
        #pragma unroll
        for (int m = 0; m < 2; ++m)
            #pragma unroll
            for (int r = 0; r < 4; ++r) hq[q][m][r] = 0.f;

    const float nL2E = -1.442695041f;

    __syncthreads();

    #pragma unroll 2
    for (int t = 0; t < 60; ++t) {
        const short* rb = hbuf[t & 1];
        short*       wb = hbuf[(t & 1) ^ 1];
        #pragma unroll
        for (int q = 0; q < 2; ++q) {
            // B-frags: B[k][n=l15] = h[batch q*16+l15][hid k], swizzled chunks
            short8 af[4];
            #pragma unroll
            for (int kt = 0; kt < 4; ++kt)
                af[kt] = *(const short8*)(rb + (q * 16 + l15) * 128 + (((kt * 4 + l4) ^ l15) & 15) * 8);

            // output head for h_t (out column t-1), rotated across waves
            if (t > 0 && wid == ((q + t) & 3)) {
                f32x4 oa = (f32x4){0.f, 0.f, 0.f, 0.f};
                #pragma unroll
                for (int kt = 0; kt < 4; ++kt) {
                    short8 wo = {0, 0, 0, 0, 0, 0, 0, 0};
                    if (l15 < 3) wo = *(const short8*)(wobuf + l15 * 136 + kt * 32 + l4 * 8);
                    oa = MFMA16(wo, af[kt], oa);
                }
                if (l4 == 0) {
                    float* op = out + (size_t)(b0 + q * 16 + l15) * 180 + (t - 1) * 3;
                    op[0] = oa[0] + bo0; op[1] = oa[1] + bo1; op[2] = oa[2] + bo2;
                }
            }

            #pragma unroll
            for (int m = 0; m < 2; ++m) {
                // gh^T = W_hh * h^T (+ bias C-init)
                f32x4 aR = initR[q][m], aZ = initZ[q][m], aN = bNh[m];
                #pragma unroll
                for (int kt = 0; kt < 4; ++kt) {
                    aR = MFMA16(wfrag[m][0][kt], af[kt], aR);
                    aZ = MFMA16(wfrag[m][1][kt], af[kt], aZ);
                    aN = MFMA16(wfrag[m][2][kt], af[kt], aN);
                }
                // gates; lane holds 4 consecutive hid dims of batch row q*16+l15
                float hn[4];
                #pragma unroll
                for (int r = 0; r < 4; ++r) {
                    float eA = __builtin_amdgcn_exp2f(aR[r] * nL2E);
                    float eB = __builtin_amdgcn_exp2f(aZ[r] * nL2E);
                    float A  = 1.0f + eA, Bv = 1.0f + eB;
                    float R  = __builtin_amdgcn_rcpf(A * Bv);   // shared rcp
                    float rr = R * Bv;                          // sigmoid(aR)
                    float zz = R * A;                           // sigmoid(aZ)
                    float sn = fmaf(rr, aN[r], giN[q][m][r]);
                    float eC = __builtin_amdgcn_exp2f(sn * (2.0f * nL2E));
                    float nn = fmaf(2.0f, __builtin_amdgcn_rcpf(1.0f + eC), -1.0f);  // tanh
                    hn[r] = fmaf(zz, hq[q][m][r] - nn, nn);
                    hq[q][m][r] = hn[r];
                }
                uint2 pk;
                pk.x = cvtpk(hn[0], hn[1]);
                pk.y = cvtpk(hn[2], hn[3]);
                const int s8 = (wid << 3) | (m << 2) | l4;   // hid/4 slot
                *(uint2*)(wb + (q * 16 + l15) * 128 + (((s8 >> 1) ^ l15) & 15) * 8 + (s8 & 1) * 4) = pk;
            }
        }
        __syncthreads();
    }

    // epilogue: out column 59 from h_60 (in hbuf[0])
    if (wid < 2) {
        const int q = wid;
        const short* rb = hbuf[0];
        f32x4 oa = (f32x4){0.f, 0.f, 0.f, 0.f};
        #pragma unroll
        for (int kt = 0; kt < 4; ++kt) {
            short8 af = *(const short8*)(rb + (q * 16 + l15) * 128 + (((kt * 4 + l4) ^ l15) & 15) * 8);
            short8 wo = {0, 0, 0, 0, 0, 0, 0, 0};
            if (l15 < 3) wo = *(const short8*)(wobuf + l15 * 136 + kt * 32 + l4 * 8);
            oa = MFMA16(wo, af, oa);
        }
        if (l4 == 0) {
            float* op = out + (size_t)(b0 + q * 16 + l15) * 180 + 59 * 3;
            op[0] = oa[0] + bo0; op[1] = oa[1] + bo1; op[2] = oa[2] + bo2;
        }
    }
}

extern "C" void kernel_launch(void* const* d_in, const int* in_sizes, int n_in,
                              void* d_out, int out_size, void* d_ws, size_t ws_size,
                              hipStream_t stream) {
    const float* x     = (const float*)d_in[0];
    const float* W_ih  = (const float*)d_in[1];
    const float* W_hh  = (const float*)d_in[2];
    const float* b_ih  = (const float*)d_in[3];
    const float* b_hh  = (const float*)d_in[4];
    const float* W_out = (const float*)d_in[5];
    const float* b_out = (const float*)d_in[6];
    float* out = (float*)d_out;

    const int B = in_sizes[0] / 256;   // 16384
    hipLaunchKernelGGL(gru_traj_kernel, dim3(B / 32), dim3(256), 0, stream,
                       x, W_ih, W_hh, b_ih, b_hh, W_out, b_out, out);
}

// Round 6
// 167.269 us; speedup vs baseline: 1.0411x; 1.0411x over previous
//
#include <hip/hip_runtime.h>

// GRU trajectory decoder, fused single kernel. B=16384, D=256, HID=128, T=60, O=3.
// R6: occupancy push -> 4 waves/SIMD (16 waves/CU). 512-thr blocks (8 waves),
// 32 batch rows/block, grid=512 -> 2 blocks/CU. Wave w owns hid [16w,16w+16):
// wfrag = 48 VGPR. R/Z gi accumulators live in LDS (wave-private, re-read as
// MFMA C-init each step, 2x ds_read_b128); R/Z weights+biases prescaled by
// -log2e so exp2 inputs come straight from MFMA. Total regs ~120 < 128 cap
// (__launch_bounds__(512,4)); R2-style spill avoided since persistent ~75.
// h through double-buffered XOR-swizzled LDS tile; one barrier per step.

typedef __attribute__((ext_vector_type(8))) short short8;
typedef __attribute__((ext_vector_type(4))) float f32x4;

#define MFMA16(a, b, c) __builtin_amdgcn_mfma_f32_16x16x32_bf16((a), (b), (c), 0, 0, 0)

__device__ __forceinline__ short f2bf(float x) {
    union { float f; unsigned u; } v; v.f = x;
    unsigned r = v.u + 0x7FFFu + ((v.u >> 16) & 1u);   // RNE
    return (short)(r >> 16);
}

__device__ __forceinline__ unsigned cvtpk(float lo, float hi) {
    unsigned d;
    asm("v_cvt_pk_bf16_f32 %0, %1, %2" : "=v"(d) : "v"(lo), "v"(hi));
    return d;
}

__device__ __forceinline__ short8 cvt8(const float* __restrict__ p) {
    f32x4 a = *(const f32x4*)p;
    f32x4 b = *(const f32x4*)(p + 4);
    short8 r;
    r[0] = f2bf(a[0]); r[1] = f2bf(a[1]); r[2] = f2bf(a[2]); r[3] = f2bf(a[3]);
    r[4] = f2bf(b[0]); r[5] = f2bf(b[1]); r[6] = f2bf(b[2]); r[7] = f2bf(b[3]);
    return r;
}
// scaled variant (for R/Z gate weights: fold -log2e into the weight)
__device__ __forceinline__ short8 cvt8s(const float* __restrict__ p, float s) {
    f32x4 a = *(const f32x4*)p;
    f32x4 b = *(const f32x4*)(p + 4);
    short8 r;
    r[0] = f2bf(a[0] * s); r[1] = f2bf(a[1] * s); r[2] = f2bf(a[2] * s); r[3] = f2bf(a[3] * s);
    r[4] = f2bf(b[0] * s); r[5] = f2bf(b[1] * s); r[6] = f2bf(b[2] * s); r[7] = f2bf(b[3] * s);
    return r;
}

__global__ __launch_bounds__(512, 4) void gru_traj_kernel(
    const float* __restrict__ x,      // [B,256]
    const float* __restrict__ W_ih,   // [384,256]
    const float* __restrict__ W_hh,   // [384,128]
    const float* __restrict__ b_ih,   // [384]
    const float* __restrict__ b_hh,   // [384]
    const float* __restrict__ W_out,  // [3,128]
    const float* __restrict__ b_out,  // [3]
    float* __restrict__ out)          // [B,60,3]
{
    const int tid  = threadIdx.x;
    const int wid  = tid >> 6;          // wave 0..7 -> 16 hid dims
    const int lane = tid & 63;
    const int l15  = lane & 15;
    const int l4   = lane >> 4;         // 0..3
    const int b0   = blockIdx.x << 5;   // 32 batch rows per block
    const int hb   = wid << 4;          // wave's hid base

    const float SCL  = -1.442695041f;   // -log2(e)
    const float SCL2 = -2.885390082f;   // -2*log2(e)

    // h^T staging: [32 batch rows][128 hid] bf16, 16B-chunk XOR swizzle, dbuf
    __shared__ short hbuf[2][32 * 128];
    __shared__ float gibuf[2 * 8 * 2 * 256];  // [g(R,Z)][wave][q][lane*4] f32, prescaled
    __shared__ short wobuf[3 * 136];          // W_out bf16, padded rows

    {   // h_0 = 0
        int* z = (int*)hbuf[0];
        #pragma unroll
        for (int i = 0; i < 4; ++i) z[tid + i * 512] = 0;
    }
    if (tid < 384) wobuf[(tid >> 7) * 136 + (tid & 127)] = f2bf(W_out[tid]);

    // ---- persistent W_hh A-frags: A[m=l15][k] = W_hh[g*128+hb+l15][k]
    // R/Z gates prescaled by -log2e.
    short8 wfrag[3][4];
    #pragma unroll
    for (int kt = 0; kt < 4; ++kt) {
        wfrag[0][kt] = cvt8s(W_hh + (size_t)(      hb + l15) * 128 + kt * 32 + l4 * 8, SCL);
        wfrag[1][kt] = cvt8s(W_hh + (size_t)(128 + hb + l15) * 128 + kt * 32 + l4 * 8, SCL);
        wfrag[2][kt] = cvt8 (W_hh + (size_t)(256 + hb + l15) * 128 + kt * 32 + l4 * 8);
    }

    // biases over this lane's 4 hid dims (D rows l4*4+r)
    const int bbase = hb + l4 * 4;
    const f32x4 bR4 = (*(const f32x4*)(b_ih + bbase)       + *(const f32x4*)(b_hh + bbase))       * SCL;
    const f32x4 bZ4 = (*(const f32x4*)(b_ih + 128 + bbase) + *(const f32x4*)(b_hh + 128 + bbase)) * SCL;
    const f32x4 bNi = *(const f32x4*)(b_ih + 256 + bbase);
    const f32x4 bNh = *(const f32x4*)(b_hh + 256 + bbase);
    const float bo0 = b_out[0], bo1 = b_out[1], bo2 = b_out[2];

    // ---- prologue: gi^T = W_ih * x^T per batch-chunk q (prescaled R/Z) ----
    f32x4 giN[2];
    {
        f32x4 initR[2], initZ[2];
        #pragma unroll
        for (int q = 0; q < 2; ++q) { initR[q] = bR4; initZ[q] = bZ4; giN[q] = bNi; }
        #pragma unroll
        for (int kt = 0; kt < 8; ++kt) {
            short8 a0 = cvt8s(W_ih + (size_t)(      hb + l15) * 256 + kt * 32 + l4 * 8, SCL);
            short8 a1 = cvt8s(W_ih + (size_t)(128 + hb + l15) * 256 + kt * 32 + l4 * 8, SCL);
            short8 a2 = cvt8 (W_ih + (size_t)(256 + hb + l15) * 256 + kt * 32 + l4 * 8);
            #pragma unroll
            for (int q = 0; q < 2; ++q) {
                short8 bx = cvt8(x + (size_t)(b0 + q * 16 + l15) * 256 + kt * 32 + l4 * 8);
                initR[q] = MFMA16(a0, bx, initR[q]);
                initZ[q] = MFMA16(a1, bx, initZ[q]);
                giN [q] = MFMA16(a2, bx, giN [q]);
            }
        }
        // park R/Z gi in LDS (wave-private; re-read as MFMA C-init each step)
        #pragma unroll
        for (int q = 0; q < 2; ++q) {
            *(f32x4*)(gibuf + ((0 * 8 + wid) * 2 + q) * 256 + lane * 4) = initR[q];
            *(f32x4*)(gibuf + ((1 * 8 + wid) * 2 + q) * 256 + lane * 4) = initZ[q];
        }
    }

    float hq[2][4];
    #pragma unroll
    for (int q = 0; q < 2; ++q)
        #pragma unroll
        for (int r = 0; r < 4; ++r) hq[q][r] = 0.f;

    const int s8 = (wid << 2) | l4;   // lane's 8B slot (hid/4) in an h row

    __syncthreads();

    #pragma unroll 2
    for (int t = 0; t < 60; ++t) {
        const short* rb = hbuf[t & 1];
        short*       wb = hbuf[(t & 1) ^ 1];
        #pragma unroll
        for (int q = 0; q < 2; ++q) {
            // B-frags: B[k][n=l15] = h[batch q*16+l15][hid k], swizzled chunks
            short8 af[4];
            #pragma unroll
            for (int kt = 0; kt < 4; ++kt)
                af[kt] = *(const short8*)(rb + (q * 16 + l15) * 128 + (((kt * 4 + l4) ^ l15) & 15) * 8);

            // output head for h_t (out column t-1), rotated across waves
            if (t > 0 && wid == ((q + t) & 7)) {
                f32x4 oa = (f32x4){0.f, 0.f, 0.f, 0.f};
                #pragma unroll
                for (int kt = 0; kt < 4; ++kt) {
                    short8 wo = {0, 0, 0, 0, 0, 0, 0, 0};
                    if (l15 < 3) wo = *(const short8*)(wobuf + l15 * 136 + kt * 32 + l4 * 8);
                    oa = MFMA16(wo, af[kt], oa);
                }
                if (l4 == 0) {
                    float* op = out + (size_t)(b0 + q * 16 + l15) * 180 + (t - 1) * 3;
                    op[0] = oa[0] + bo0; op[1] = oa[1] + bo1; op[2] = oa[2] + bo2;
                }
            }

            // C-init from LDS (prescaled gi_r/gi_z + biases)
            f32x4 aR = *(const f32x4*)(gibuf + ((0 * 8 + wid) * 2 + q) * 256 + lane * 4);
            f32x4 aZ = *(const f32x4*)(gibuf + ((1 * 8 + wid) * 2 + q) * 256 + lane * 4);
            f32x4 aN = bNh;
            #pragma unroll
            for (int kt = 0; kt < 4; ++kt) {
                aR = MFMA16(wfrag[0][kt], af[kt], aR);
                aZ = MFMA16(wfrag[1][kt], af[kt], aZ);
                aN = MFMA16(wfrag[2][kt], af[kt], aN);
            }
            // gates; aR/aZ already = -log2e * preact -> exp2 direct
            float hn[4];
            #pragma unroll
            for (int r = 0; r < 4; ++r) {
                float eA = __builtin_amdgcn_exp2f(aR[r]);
                float eB = __builtin_amdgcn_exp2f(aZ[r]);
                float A  = 1.0f + eA, Bv = 1.0f + eB;
                float R  = __builtin_amdgcn_rcpf(A * Bv);     // shared rcp
                float rr = R * Bv;                            // sigmoid r
                float zz = R * A;                             // sigmoid z
                float sn = fmaf(rr, aN[r], giN[q][r]);
                float eC = __builtin_amdgcn_exp2f(sn * SCL2);
                float nn = fmaf(2.0f, __builtin_amdgcn_rcpf(1.0f + eC), -1.0f);  // tanh
                hn[r] = fmaf(zz, hq[q][r] - nn, nn);
                hq[q][r] = hn[r];
            }
            uint2 pk;
            pk.x = cvtpk(hn[0], hn[1]);
            pk.y = cvtpk(hn[2], hn[3]);
            *(uint2*)(wb + (q * 16 + l15) * 128 + (((s8 >> 1) ^ l15) & 15) * 8 + (s8 & 1) * 4) = pk;
        }
        __syncthreads();
    }

    // epilogue: out column 59 from h_60 (in hbuf[0])
    if (wid < 2) {
        const int q = wid;
        const short* rb = hbuf[0];
        f32x4 oa = (f32x4){0.f, 0.f, 0.f, 0.f};
        #pragma unroll
        for (int kt = 0; kt < 4; ++kt) {
            short8 af = *(const short8*)(rb + (q * 16 + l15) * 128 + (((kt * 4 + l4) ^ l15) & 15) * 8);
            short8 wo = {0, 0, 0, 0, 0, 0, 0, 0};
            if (l15 < 3) wo = *(const short8*)(wobuf + l15 * 136 + kt * 32 + l4 * 8);
            oa = MFMA16(wo, af, oa);
        }
        if (l4 == 0) {
            float* op = out + (size_t)(b0 + q * 16 + l15) * 180 + 59 * 3;
            op[0] = oa[0] + bo0; op[1] = oa[1] + bo1; op[2] = oa[2] + bo2;
        }
    }
}

extern "C" void kernel_launch(void* const* d_in, const int* in_sizes, int n_in,
                              void* d_out, int out_size, void* d_ws, size_t ws_size,
                              hipStream_t stream) {
    const float* x     = (const float*)d_in[0];
    const float* W_ih  = (const float*)d_in[1];
    const float* W_hh  = (const float*)d_in[2];
    const float* b_ih  = (const float*)d_in[3];
    const float* b_hh  = (const float*)d_in[4];
    const float* W_out = (const float*)d_in[5];
    const float* b_out = (const float*)d_in[6];
    float* out = (float*)d_out;

    const int B = in_sizes[0] / 256;   // 16384
    hipLaunchKernelGGL(gru_traj_kernel, dim3(B / 32), dim3(512), 0, stream,
                       x, W_ih, W_hh, b_ih, b_hh, W_out, b_out, out);
}